// Round 4
// baseline (483.582 us; speedup 1.0000x reference)
//
#include <hip/hip_runtime.h>
#include <hip/hip_bf16.h>
#include <math.h>

typedef __attribute__((ext_vector_type(8))) short short8;
typedef __attribute__((ext_vector_type(16))) float f32x16;

static constexpr int B  = 32;
static constexpr int S  = 2048;
static constexpr int D  = 512;
static constexpr int KE = 1024;   // encoder feature dim = 2*ENC_H
static constexpr int IN = 1536;   // D + KE

__device__ __forceinline__ unsigned pk2(float lo, float hi) {
    __hip_bfloat162 t = __float22bfloat162_rn(make_float2(lo, hi));
    unsigned u;
    __builtin_memcpy(&u, &t, 4);
    return u;
}

__device__ __forceinline__ short8 pack8(float4 f0, float4 f1) {
    unsigned u[4] = { pk2(f0.x, f0.y), pk2(f0.z, f0.w), pk2(f1.x, f1.y), pk2(f1.z, f1.w) };
    short8 r;
    __builtin_memcpy(&r, u, 16);
    return r;
}

// fast tanh via exp: (e^2x - 1)/(e^2x + 1)
__device__ __forceinline__ float tanh_fast(float x) {
    float e = __expf(2.0f * x);
    return (e - 1.0f) * __builtin_amdgcn_rcpf(e + 1.0f);
}

// async global->LDS DMA, 16B per lane, wave-uniform LDS base
typedef const __attribute__((address_space(1))) unsigned int guint;
typedef __attribute__((address_space(3))) unsigned int luint;
__device__ __forceinline__ void gload_lds16(const void* g, void* l) {
    __builtin_amdgcn_global_load_lds((guint*)g, (luint*)l, 16, 0, 0);
}

// ---------- kernel 0: fused prep (B-frag pack + u projection + ws zeroing) ----------
__global__ void k_prep(const float* __restrict__ attn_w,
                       const float* __restrict__ hidden,
                       const float* __restrict__ attn_b,
                       unsigned short* __restrict__ Bf,
                       float* __restrict__ u,
                       float* __restrict__ num,
                       float* __restrict__ den) {
    if (blockIdx.x < 256) {
        int o = blockIdx.x * 256 + threadIdx.x;   // short8 index, 65536 total
        int l6  = o & 63;
        int grp = o >> 6;
        int d = (grp & 15) * 32 + (l6 & 31);
        int k = (grp >> 4) * 16 + (l6 >> 5) * 8;
        const float* src = attn_w + (size_t)d * IN + 512 + k;
        float4 f0 = *(const float4*)src;
        float4 f1 = *(const float4*)(src + 4);
        ((short8*)Bf)[o] = pack8(f0, f1);
    } else {
        // u[b][d] = attn_b[d] + dot(hidden[b], attn_w[d][0:512])
        // coalesced: 16 lanes cooperate per d (contiguous 256B segments), shfl reduce
        int bx = blockIdx.x - 256;        // 0..63
        // ---- workspace zeroing (replaces hipMemsetAsync dispatch) ----
        {
            int gid = bx * 256 + threadIdx.x;          // 0..16383
            ((float2*)num)[gid] = make_float2(0.f, 0.f);  // 32768 floats
            if (bx == 0 && threadIdx.x < 64) den[threadIdx.x] = 0.f;  // den[32] + cnt[32]
        }
        int b  = bx >> 1;
        int dh = bx & 1;
        int w  = threadIdx.x >> 6;        // wave 0..3
        int l  = threadIdx.x & 63;
        int j  = l & 15;                  // k-segment lane
        int dsub = l >> 4;                // 0..3 (d within wave-group)
        const float* h = hidden + b * D;
        float4 hv[8];
        #pragma unroll
        for (int i = 0; i < 8; i++) hv[i] = *(const float4*)(h + i * 64 + j * 4);
        #pragma unroll
        for (int p = 0; p < 16; p++) {
            int d = dh * 256 + p * 16 + w * 4 + dsub;
            const float* wr = attn_w + (size_t)d * IN + j * 4;
            float a = 0.f;
            #pragma unroll
            for (int i = 0; i < 8; i++) {
                float4 wv = *(const float4*)(wr + i * 64);
                a += hv[i].x * wv.x + hv[i].y * wv.y + hv[i].z * wv.z + hv[i].w * wv.w;
            }
            #pragma unroll
            for (int off = 8; off >= 1; off >>= 1) a += __shfl_xor(a, off);
            if (j == 0) u[b * D + d] = a + attn_b[d];
        }
    }
}

// ---------- kernel 1: FUSED scores + exp + context + last-block normalize ----------
// block: 64 s x 512 d, 4 waves; wave w owns d-slice [w*128,(w+1)*128).
// Staging: global_load_lds (DMA, fp32 in LDS), source pre-swizzled so the
// swizzled ds_read_b128 fragment reads are bank-optimal; bf16 convert at
// fragment-read time. One __syncthreads per chunk; DMA for chunk c+1 issued
// during compute of c, drained by the compiler's vmcnt(0) at the next barrier.
// Final: per-b arrival counter; last block normalizes num/den -> out.
// Protocol (threadfence-reduction pattern, agent scope per Guideline 16):
//   all threads atomicAdd -> __syncthreads -> tid0 fence + ACQ_REL fetch_add;
//   winner's acquire synchronizes-with losers' releases -> reads are ordered.
#define LOADB(K, DST) do {                                     \
    _Pragma("unroll")                                          \
    for (int _jt = 0; _jt < 4; _jt++)                          \
        DST[_jt] = bb[(size_t)(K) * 1024 + _jt * 64];          \
} while (0)

__global__ __launch_bounds__(256, 2) void k_fused(
    const float* __restrict__ enc, const unsigned short* __restrict__ Bfrag,
    const float* __restrict__ u, const float* __restrict__ v_w,
    const float* __restrict__ v_b, const int* __restrict__ lengths,
    float* __restrict__ num, float* __restrict__ den,
    int* __restrict__ cnt, float* __restrict__ out)
{
    __shared__ float4 ldsA[2][1024];   // 2 x 16 KB fp32 chunk [row 0..63][slot 0..15]
    __shared__ float sPart[4][64];
    __shared__ float sExp[64];
    __shared__ int sWin;

    const int b   = blockIdx.y;
    const int s0  = blockIdx.x * 64;
    const int len = lengths[b];
    if (s0 >= len) return;

    const int tid = threadIdx.x;
    const int w   = tid >> 6;     // wave 0..3
    const int l   = tid & 63;     // lane

    const float* encb = enc + ((size_t)b * S + s0) * KE;

    // ---- staging source addresses (inverse-swizzled global) ----
    // issue i: wave-uniform LDS base = buf + (i*4+w)*1KB; lane l lands at
    // row r = (i*4+w)*4 + (l>>4), phys slot p = l&15. Must contain logical
    // slot s = p ^ (r&15); note r&15 = w*4 + (l>>4), independent of i.
    const int rsub = l >> 4;                       // 0..3
    const int xorv = (l & 15) ^ (w * 4 + rsub);    // logical slot for this lane
    const float* aSrc = encb + (size_t)(w * 4 + rsub) * KE + 4 * xorv;

    const short8* bb = (const short8*)Bfrag + (w * 4) * 64 + l;

    f32x16 acc[2][4];
    #pragma unroll
    for (int mt = 0; mt < 2; mt++)
        #pragma unroll
        for (int jt = 0; jt < 4; jt++)
            #pragma unroll
            for (int e = 0; e < 16; e++) acc[mt][jt][e] = 0.f;

    short8 pb[2][4];
    LOADB(0, pb[0]);
    LOADB(1, pb[1]);

    // fragment read constants: lane reads rows m0, m0+32; float cols
    // t2*16 + (l>>5)*8 .. +7 = slots sq, sq+1 (swizzled by row&15)
    const int m0  = l & 31;
    const int x15 = m0 & 15;
    const int hi2 = (l >> 5) * 2;

    // prologue: stage chunk 0 into buf 0
    #pragma unroll
    for (int i = 0; i < 4; i++)
        gload_lds16(aSrc + (size_t)i * 16 * KE, (void*)&ldsA[0][(i * 4 + w) * 64]);

    #pragma unroll 1
    for (int c = 0; c < 16; ++c) {
        __syncthreads();   // drains DMA for chunk c (vmcnt0) + frag reads of c-1 (lgkm0)
        if (c < 15) {
            const float* src = aSrc + (c + 1) * 64;
            float4* bufn = ldsA[(c + 1) & 1];
            #pragma unroll
            for (int i = 0; i < 4; i++)
                gload_lds16(src + (size_t)i * 16 * KE, (void*)&bufn[(i * 4 + w) * 64]);
        }
        const float4* bf = (const float4*)ldsA[c & 1];
        #pragma unroll
        for (int t2 = 0; t2 < 4; ++t2) {
            const int sq = t2 * 4 + hi2;
            const int p0 = sq ^ x15;
            const int p1 = (sq + 1) ^ x15;
            float4 f00 = bf[m0 * 16 + p0];
            float4 f01 = bf[m0 * 16 + p1];
            float4 f10 = bf[(m0 + 32) * 16 + p0];
            float4 f11 = bf[(m0 + 32) * 16 + p1];
            short8 a0 = pack8(f00, f01);
            short8 a1 = pack8(f10, f11);
            const int bp = t2 & 1;
            #pragma unroll
            for (int jt = 0; jt < 4; jt++) {
                acc[0][jt] = __builtin_amdgcn_mfma_f32_32x32x16_bf16(a0, pb[bp][jt], acc[0][jt], 0, 0, 0);
                acc[1][jt] = __builtin_amdgcn_mfma_f32_32x32x16_bf16(a1, pb[bp][jt], acc[1][jt], 0, 0, 0);
            }
            LOADB((c * 4 + t2 + 2) & 63, pb[bp]);
        }
    }

    // ---- epilogue A: score_part = sum_d v[d]*tanh(pre + u[d]) ----
    // C/D layout (32x32): col = lane&31, row = (reg&3) + 8*(reg>>2) + 4*(lane>>5)
    float vv[4], uu[4];
    const float* ub = u + b * D;
    #pragma unroll
    for (int jt = 0; jt < 4; jt++) {
        int d = w * 128 + jt * 32 + (l & 31);
        vv[jt] = v_w[d];
        uu[jt] = ub[d];
    }
    float red[2][16];
    #pragma unroll
    for (int mt = 0; mt < 2; mt++)
        #pragma unroll
        for (int r = 0; r < 16; r++) {
            float s = 0.f;
            #pragma unroll
            for (int jt = 0; jt < 4; jt++)
                s += vv[jt] * tanh_fast(acc[mt][jt][r] + uu[jt]);
            red[mt][r] = s;
        }
    #pragma unroll
    for (int off = 16; off >= 1; off >>= 1)
        #pragma unroll
        for (int mt = 0; mt < 2; mt++)
            #pragma unroll
            for (int r = 0; r < 16; r++)
                red[mt][r] += __shfl_xor(red[mt][r], off);
    if ((l & 31) == 0) {
        int hb = (l >> 5) * 4;
        #pragma unroll
        for (int mt = 0; mt < 2; mt++)
            #pragma unroll
            for (int r = 0; r < 16; r++)
                sPart[w][mt * 32 + (r & 3) + 8 * (r >> 2) + hb] = red[mt][r];
    }
    __syncthreads();

    // ---- epilogue B: w = exp(score) (|score|<=~23, no max needed), masked; den ----
    if (tid < 64) {
        float sc = sPart[0][tid] + sPart[1][tid] + sPart[2][tid] + sPart[3][tid] + v_b[0];
        float wexp = (s0 + tid < len) ? __expf(sc) : 0.f;
        sExp[tid] = wexp;
        #pragma unroll
        for (int off = 32; off >= 1; off >>= 1) wexp += __shfl_xor(wexp, off);
        if (tid == 0) atomicAdd(den + b, wexp);
    }
    __syncthreads();

    // ---- epilogue C: num[b][e] += sum_s w_s * enc[s][e] (enc L2-warm) ----
    const float4* e4 = (const float4*)encb;
    float4 cacc[4];
    #pragma unroll
    for (int j = 0; j < 4; j++) cacc[j] = make_float4(0.f, 0.f, 0.f, 0.f);
    #pragma unroll
    for (int i = 0; i < 16; i++) {
        #pragma unroll
        for (int j = 0; j < 4; j++) {
            float wgt = sExp[i * 4 + j];
            float4 v = e4[(size_t)(i * 4 + j) * 256 + tid];
            cacc[j].x += wgt * v.x; cacc[j].y += wgt * v.y;
            cacc[j].z += wgt * v.z; cacc[j].w += wgt * v.w;
        }
    }
    #pragma unroll
    for (int j = 1; j < 4; j++) {
        cacc[0].x += cacc[j].x; cacc[0].y += cacc[j].y;
        cacc[0].z += cacc[j].z; cacc[0].w += cacc[j].w;
    }
    float* o = num + b * KE + tid * 4;
    atomicAdd(o + 0, cacc[0].x);
    atomicAdd(o + 1, cacc[0].y);
    atomicAdd(o + 2, cacc[0].z);
    atomicAdd(o + 3, cacc[0].w);

    // ---- epilogue D: last block for this b normalizes (replaces k_norm) ----
    __syncthreads();   // REQUIRED: all 256 threads' num-atomics precede the arrival
    if (tid == 0) {
        __threadfence();   // device-scope release of this block's contributions
        int expected = (len + 63) >> 6;
        int old = __hip_atomic_fetch_add(cnt + b, 1, __ATOMIC_ACQ_REL,
                                         __HIP_MEMORY_SCOPE_AGENT);
        sWin = (old == expected - 1);
    }
    __syncthreads();
    if (sWin) {
        float dv = __hip_atomic_load(den + b, __ATOMIC_RELAXED,
                                     __HIP_MEMORY_SCOPE_AGENT);
        float inv = 1.f / dv;
        #pragma unroll
        for (int i = 0; i < 4; i++) {
            int e = i * 256 + tid;
            float nv = __hip_atomic_load(num + b * KE + e, __ATOMIC_RELAXED,
                                         __HIP_MEMORY_SCOPE_AGENT);
            out[b * KE + e] = nv * inv;
        }
    }
}

extern "C" void kernel_launch(void* const* d_in, const int* in_sizes, int n_in,
                              void* d_out, int out_size, void* d_ws, size_t ws_size,
                              hipStream_t stream) {
    const float* enc    = (const float*)d_in[0];
    const float* hidden = (const float*)d_in[1];
    const int*   lengths= (const int*)d_in[2];
    const float* attn_w = (const float*)d_in[3];
    const float* attn_b = (const float*)d_in[4];
    const float* v_w    = (const float*)d_in[5];
    const float* v_b    = (const float*)d_in[6];
    float* out = (float*)d_out;

    // workspace layout (fp32 elements)
    float* ws  = (float*)d_ws;
    float* u   = ws;                        // 16384 floats
    float* num = u + B * D;                 // B*KE = 32768 floats
    float* den = num + B * KE;              // 32 floats
    int*   cnt = (int*)(den + B);           // 32 ints
    unsigned short* Bf = (unsigned short*)(cnt + B);  // 524288 bf16 = 1MB (16B-aligned)

    k_prep <<<dim3(320), 256, 0, stream>>>(attn_w, hidden, attn_b, Bf, u, num, den);
    k_fused<<<dim3(S / 64, B), 256, 0, stream>>>(enc, Bf, u, v_w, v_b, lengths,
                                                 num, den, cnt, out);
}

// Round 5
// 438.968 us; speedup vs baseline: 1.1016x; 1.1016x over previous
//
#include <hip/hip_runtime.h>
#include <hip/hip_bf16.h>
#include <math.h>

typedef __attribute__((ext_vector_type(8))) short short8;
typedef __attribute__((ext_vector_type(16))) float f32x16;

static constexpr int B  = 32;
static constexpr int S  = 2048;
static constexpr int D  = 512;
static constexpr int KE = 1024;   // encoder feature dim = 2*ENC_H
static constexpr int IN = 1536;   // D + KE

__device__ __forceinline__ unsigned pk2(float lo, float hi) {
    __hip_bfloat162 t = __float22bfloat162_rn(make_float2(lo, hi));
    unsigned u;
    __builtin_memcpy(&u, &t, 4);
    return u;
}

__device__ __forceinline__ short8 pack8(float4 f0, float4 f1) {
    unsigned u[4] = { pk2(f0.x, f0.y), pk2(f0.z, f0.w), pk2(f1.x, f1.y), pk2(f1.z, f1.w) };
    short8 r;
    __builtin_memcpy(&r, u, 16);
    return r;
}

// fast tanh via exp: (e^2x - 1)/(e^2x + 1)
__device__ __forceinline__ float tanh_fast(float x) {
    float e = __expf(2.0f * x);
    return (e - 1.0f) * __builtin_amdgcn_rcpf(e + 1.0f);
}

// async global->LDS DMA, 16B per lane, wave-uniform LDS base
typedef const __attribute__((address_space(1))) unsigned int guint;
typedef __attribute__((address_space(3))) unsigned int luint;
__device__ __forceinline__ void gload_lds16(const void* g, void* l) {
    __builtin_amdgcn_global_load_lds((guint*)g, (luint*)l, 16, 0, 0);
}

// ---------- kernel 0: fused prep (B-frag pack + u projection + ws zeroing) ----------
__global__ void k_prep(const float* __restrict__ attn_w,
                       const float* __restrict__ hidden,
                       const float* __restrict__ attn_b,
                       unsigned short* __restrict__ Bf,
                       float* __restrict__ u,
                       float* __restrict__ num,
                       float* __restrict__ den) {
    if (blockIdx.x < 256) {
        int o = blockIdx.x * 256 + threadIdx.x;   // short8 index, 65536 total
        int l6  = o & 63;
        int grp = o >> 6;
        int d = (grp & 15) * 32 + (l6 & 31);
        int k = (grp >> 4) * 16 + (l6 >> 5) * 8;
        const float* src = attn_w + (size_t)d * IN + 512 + k;
        float4 f0 = *(const float4*)src;
        float4 f1 = *(const float4*)(src + 4);
        ((short8*)Bf)[o] = pack8(f0, f1);
    } else {
        // u[b][d] = attn_b[d] + dot(hidden[b], attn_w[d][0:512])
        // coalesced: 16 lanes cooperate per d (contiguous 256B segments), shfl reduce
        int bx = blockIdx.x - 256;        // 0..63
        // ---- workspace zeroing (replaces hipMemsetAsync dispatch) ----
        {
            int gid = bx * 256 + threadIdx.x;          // 0..16383
            ((float2*)num)[gid] = make_float2(0.f, 0.f);  // 32768 floats
            if (bx == 0 && threadIdx.x < 32) den[threadIdx.x] = 0.f;  // den[32]
        }
        int b  = bx >> 1;
        int dh = bx & 1;
        int w  = threadIdx.x >> 6;        // wave 0..3
        int l  = threadIdx.x & 63;
        int j  = l & 15;                  // k-segment lane
        int dsub = l >> 4;                // 0..3 (d within wave-group)
        const float* h = hidden + b * D;
        float4 hv[8];
        #pragma unroll
        for (int i = 0; i < 8; i++) hv[i] = *(const float4*)(h + i * 64 + j * 4);
        #pragma unroll
        for (int p = 0; p < 16; p++) {
            int d = dh * 256 + p * 16 + w * 4 + dsub;
            const float* wr = attn_w + (size_t)d * IN + j * 4;
            float a = 0.f;
            #pragma unroll
            for (int i = 0; i < 8; i++) {
                float4 wv = *(const float4*)(wr + i * 64);
                a += hv[i].x * wv.x + hv[i].y * wv.y + hv[i].z * wv.z + hv[i].w * wv.w;
            }
            #pragma unroll
            for (int off = 8; off >= 1; off >>= 1) a += __shfl_xor(a, off);
            if (j == 0) u[b * D + d] = a + attn_b[d];
        }
    }
}

// ---------- kernel 1: FUSED scores + exp + context-accumulate ----------
// block: 64 s x 512 d, 4 waves; wave w owns d-slice [w*128,(w+1)*128).
// K-chunk = 128 floats (512 B contiguous per enc row per DMA phase -> 2x fewer
// DRAM page activations than the 64-float version; this kernel was measured
// DRAM-efficiency-bound at 722 GB/s with 256 B grains). Double-buffered
// 2 x 32 KB LDS chunks, same single-barrier-per-chunk skeleton: barrier at
// loop top drains DMA(c) (vmcnt0) + frag reads of c-1; then issue DMA(c+1)
// into the other buffer and compute chunk c.
// Swizzle: logical float4-slot s of row r stored at phys p = s ^ (r & 7)
// (involution; spreads a 32-row column read across all 8 bank-groups ->
// conflict-free ds_read_b128). DMA writes linearly; the XOR is applied to
// the per-lane GLOBAL source address (rule: linear dest + inverse-swizzled
// source + swizzled read).
#define LOADB(K, DST) do {                                     \
    _Pragma("unroll")                                          \
    for (int _jt = 0; _jt < 4; _jt++)                          \
        DST[_jt] = bb[(size_t)(K) * 1024 + _jt * 64];          \
} while (0)

__global__ __launch_bounds__(256, 2) void k_fused(
    const float* __restrict__ enc, const unsigned short* __restrict__ Bfrag,
    const float* __restrict__ u, const float* __restrict__ v_w,
    const float* __restrict__ v_b, const int* __restrict__ lengths,
    float* __restrict__ num, float* __restrict__ den)
{
    __shared__ float4 ldsA[2][2048];   // 2 x 32 KB fp32 chunk [row 0..63][slot 0..31]
    // epilogue scratch aliased into buffer 0 (free after the final loop barrier)
    float* sPart = (float*)&ldsA[0][0];     // [4][64]
    float* sExp  = sPart + 256;             // [64]

    const int b   = blockIdx.y;
    const int s0  = blockIdx.x * 64;
    const int len = lengths[b];
    if (s0 >= len) return;

    const int tid = threadIdx.x;
    const int w   = tid >> 6;     // wave 0..3
    const int l   = tid & 63;     // lane

    const float* encb = enc + ((size_t)b * S + s0) * KE;

    // ---- staging source addresses (inverse-swizzled global) ----
    // issue i: wave-uniform LDS base = buf + (i*4+w)*64 float4 (1 KB = 2 rows);
    // lane l lands at row r = 8i + 2w + (l>>5), phys slot p = l&31. Must hold
    // logical slot s = p ^ (r&7); r&7 = 2w + (l>>5), independent of i.
    const int rlo  = l >> 5;                        // 0..1
    const int xv   = (l & 31) ^ (2 * w + rlo);      // logical slot for this lane
    const float* aSrc = encb + (size_t)(2 * w + rlo) * KE + 4 * xv;

    const short8* bb = (const short8*)Bfrag + (w * 4) * 64 + l;

    f32x16 acc[2][4];
    #pragma unroll
    for (int mt = 0; mt < 2; mt++)
        #pragma unroll
        for (int jt = 0; jt < 4; jt++)
            #pragma unroll
            for (int e = 0; e < 16; e++) acc[mt][jt][e] = 0.f;

    short8 pb[2][4];
    LOADB(0, pb[0]);
    LOADB(1, pb[1]);

    // fragment read constants: lane reads rows m0, m0+32; logical slots
    // s0 = t*4 + (l>>5)*2, s0+1; phys = s ^ (m0 & 7) (same for m0+32)
    const int m0  = l & 31;
    const int xr  = m0 & 7;
    const int hi2 = (l >> 5) * 2;

    // prologue: stage chunk 0 into buf 0 (8 issues/wave, 2 rows each)
    #pragma unroll
    for (int i = 0; i < 8; i++)
        gload_lds16(aSrc + (size_t)i * 8 * KE, (void*)&ldsA[0][(i * 4 + w) * 64]);

    #pragma unroll 1
    for (int c = 0; c < 8; ++c) {
        __syncthreads();   // drains DMA for chunk c (vmcnt0) + frag reads of c-1 (lgkm0)
        if (c < 7) {
            const float* src = aSrc + (c + 1) * 128;
            float4* bufn = ldsA[(c + 1) & 1];
            #pragma unroll
            for (int i = 0; i < 8; i++)
                gload_lds16(src + (size_t)i * 8 * KE, (void*)&bufn[(i * 4 + w) * 64]);
        }
        const float4* bf = &ldsA[c & 1][0];
        #pragma unroll
        for (int t = 0; t < 8; ++t) {
            const int s0l = t * 4 + hi2;
            const int p0  = s0l ^ xr;
            const int p1  = (s0l + 1) ^ xr;
            float4 f00 = bf[m0 * 32 + p0];
            float4 f01 = bf[m0 * 32 + p1];
            float4 f10 = bf[(m0 + 32) * 32 + p0];
            float4 f11 = bf[(m0 + 32) * 32 + p1];
            short8 a0 = pack8(f00, f01);
            short8 a1 = pack8(f10, f11);
            const int bp = t & 1;
            #pragma unroll
            for (int jt = 0; jt < 4; jt++) {
                acc[0][jt] = __builtin_amdgcn_mfma_f32_32x32x16_bf16(a0, pb[bp][jt], acc[0][jt], 0, 0, 0);
                acc[1][jt] = __builtin_amdgcn_mfma_f32_32x32x16_bf16(a1, pb[bp][jt], acc[1][jt], 0, 0, 0);
            }
            LOADB((c * 8 + t + 2) & 63, pb[bp]);
        }
    }

    // ---- epilogue A: score_part = sum_d v[d]*tanh(pre + u[d]) ----
    // C/D layout (32x32): col = lane&31, row = (reg&3) + 8*(reg>>2) + 4*(lane>>5)
    float vv[4], uu[4];
    const float* ub = u + b * D;
    #pragma unroll
    for (int jt = 0; jt < 4; jt++) {
        int d = w * 128 + jt * 32 + (l & 31);
        vv[jt] = v_w[d];
        uu[jt] = ub[d];
    }
    float red[2][16];
    #pragma unroll
    for (int mt = 0; mt < 2; mt++)
        #pragma unroll
        for (int r = 0; r < 16; r++) {
            float s = 0.f;
            #pragma unroll
            for (int jt = 0; jt < 4; jt++)
                s += vv[jt] * tanh_fast(acc[mt][jt][r] + uu[jt]);
            red[mt][r] = s;
        }
    #pragma unroll
    for (int off = 16; off >= 1; off >>= 1)
        #pragma unroll
        for (int mt = 0; mt < 2; mt++)
            #pragma unroll
            for (int r = 0; r < 16; r++)
                red[mt][r] += __shfl_xor(red[mt][r], off);
    // note: sPart aliases ldsA buf0; safe — all waves passed the c=7 top
    // barrier (done reading buf0), and c=7 computes from buf1 only.
    if ((l & 31) == 0) {
        int hb = (l >> 5) * 4;
        #pragma unroll
        for (int mt = 0; mt < 2; mt++)
            #pragma unroll
            for (int r = 0; r < 16; r++)
                sPart[w * 64 + mt * 32 + (r & 3) + 8 * (r >> 2) + hb] = red[mt][r];
    }
    __syncthreads();

    // ---- epilogue B: w = exp(score) (|score|<=~23, no max needed), masked; den ----
    if (tid < 64) {
        float sc = sPart[tid] + sPart[64 + tid] + sPart[128 + tid] + sPart[192 + tid] + v_b[0];
        float wexp = (s0 + tid < len) ? __expf(sc) : 0.f;
        sExp[tid] = wexp;
        #pragma unroll
        for (int off = 32; off >= 1; off >>= 1) wexp += __shfl_xor(wexp, off);
        if (tid == 0) atomicAdd(den + b, wexp);
    }
    __syncthreads();

    // ---- epilogue C: num[b][e] += sum_s w_s * enc[s][e] (enc L2-warm) ----
    const float4* e4 = (const float4*)encb;
    float4 cacc[4];
    #pragma unroll
    for (int j = 0; j < 4; j++) cacc[j] = make_float4(0.f, 0.f, 0.f, 0.f);
    #pragma unroll
    for (int i = 0; i < 16; i++) {
        #pragma unroll
        for (int j = 0; j < 4; j++) {
            float wgt = sExp[i * 4 + j];
            float4 v = e4[(size_t)(i * 4 + j) * 256 + tid];
            cacc[j].x += wgt * v.x; cacc[j].y += wgt * v.y;
            cacc[j].z += wgt * v.z; cacc[j].w += wgt * v.w;
        }
    }
    #pragma unroll
    for (int j = 1; j < 4; j++) {
        cacc[0].x += cacc[j].x; cacc[0].y += cacc[j].y;
        cacc[0].z += cacc[j].z; cacc[0].w += cacc[j].w;
    }
    float* o = num + b * KE + tid * 4;
    atomicAdd(o + 0, cacc[0].x);
    atomicAdd(o + 1, cacc[0].y);
    atomicAdd(o + 2, cacc[0].z);
    atomicAdd(o + 3, cacc[0].w);
}

// ---------- kernel 2: out = num / den ----------
__global__ void k_norm(const float* __restrict__ num, const float* __restrict__ den,
                       float* __restrict__ out) {
    int b = blockIdx.x;
    int t = threadIdx.x;
    float inv = 1.f / den[b];
    float4 v = ((const float4*)(num + b * KE))[t];
    v.x *= inv; v.y *= inv; v.z *= inv; v.w *= inv;
    ((float4*)(out + b * KE))[t] = v;
}

extern "C" void kernel_launch(void* const* d_in, const int* in_sizes, int n_in,
                              void* d_out, int out_size, void* d_ws, size_t ws_size,
                              hipStream_t stream) {
    const float* enc    = (const float*)d_in[0];
    const float* hidden = (const float*)d_in[1];
    const int*   lengths= (const int*)d_in[2];
    const float* attn_w = (const float*)d_in[3];
    const float* attn_b = (const float*)d_in[4];
    const float* v_w    = (const float*)d_in[5];
    const float* v_b    = (const float*)d_in[6];
    float* out = (float*)d_out;

    // workspace layout (fp32 elements)
    float* ws  = (float*)d_ws;
    float* u   = ws;                        // 16384 floats
    float* num = u + B * D;                 // B*KE = 32768 floats
    float* den = num + B * KE;              // 32 floats
    unsigned short* Bf = (unsigned short*)(den + 32);  // 524288 bf16 = 1MB (16B-aligned)

    k_prep <<<dim3(320), 256, 0, stream>>>(attn_w, hidden, attn_b, Bf, u, num, den);
    k_fused<<<dim3(S / 64, B), 256, 0, stream>>>(enc, Bf, u, v_w, v_b, lengths, num, den);
    k_norm <<<dim3(B), 256, 0, stream>>>(num, den, out);
}